// Round 1
// baseline (418.257 us; speedup 1.0000x reference)
//
#include <hip/hip_runtime.h>
#include <hip/hip_bf16.h>

#define N_POINTS 100000
#define K_VOL 27
#define PAIRS 60000
#define CCH 64                       // C_IN == C_OUT == 64
#define TILES_PER_K (PAIRS / 16)     // 3750 (exact)
#define BX 64                        // blocks per kernel-offset
#define NWAVES 4                     // waves per block (256 threads)

typedef __bf16 bf16x8 __attribute__((ext_vector_type(8)));
typedef float f32x4 __attribute__((ext_vector_type(4)));

// out[i][c] = bias[c]  (d_out is re-poisoned before every timed call)
__global__ __launch_bounds__(256) void init_out_kernel(
    const float* __restrict__ bias, float* __restrict__ out) {
  int tid = blockIdx.x * blockDim.x + threadIdx.x;  // over N_POINTS*16 float4s
  int c4 = tid & 15;                                 // which float4 of the 64-ch row
  float4 b = ((const float4*)bias)[c4];
  ((float4*)out)[tid] = b;
}

__global__ __launch_bounds__(256) void spconv_kernel(
    const float* __restrict__ input,   // [N, 64]
    const float* __restrict__ weight,  // [27, 64, 64]  (ci, co)
    const int* __restrict__ in_map,    // [27, PAIRS]
    const int* __restrict__ out_map,   // [27, PAIRS]
    float* __restrict__ out)           // [N, 64]
{
  const int k    = blockIdx.y;
  const int lane = threadIdx.x & 63;
  const int wave = threadIdx.x >> 6;
  const int col  = lane & 15;
  const int quad = lane >> 4;

  // ---- B fragments for this kernel offset: registers, reused across all tiles.
  // B[k=ci][n=co]: n = lane&15 (+16*nt), k = quad*8 + j (+32*s)
  const float* Wk = weight + k * (CCH * CCH);
  bf16x8 bfrag[4][2];
#pragma unroll
  for (int nt = 0; nt < 4; ++nt) {
    int co = nt * 16 + col;
#pragma unroll
    for (int s = 0; s < 2; ++s) {
      int ci0 = s * 32 + quad * 8;
      bf16x8 f;
#pragma unroll
      for (int j = 0; j < 8; ++j)
        f[j] = (__bf16)Wk[(ci0 + j) * CCH + co];
      bfrag[nt][s] = f;
    }
  }

  const int* im = in_map + k * PAIRS;
  const int* om = out_map + k * PAIRS;

  for (int tile = blockIdx.x * NWAVES + wave; tile < TILES_PER_K;
       tile += BX * NWAVES) {
    const int pbase = tile * 16;

    // ---- gather A fragments: A[m=pair][k=ci], m = lane&15, ci = s*32+quad*8+j
    int rin = im[pbase + col];
    const float* arow = input + rin * CCH;
    bf16x8 afrag[2];
#pragma unroll
    for (int s = 0; s < 2; ++s) {
      const float4 x0 = *(const float4*)(arow + s * 32 + quad * 8);
      const float4 x1 = *(const float4*)(arow + s * 32 + quad * 8 + 4);
      bf16x8 f;
      f[0] = (__bf16)x0.x; f[1] = (__bf16)x0.y;
      f[2] = (__bf16)x0.z; f[3] = (__bf16)x0.w;
      f[4] = (__bf16)x1.x; f[5] = (__bf16)x1.y;
      f[6] = (__bf16)x1.z; f[7] = (__bf16)x1.w;
      afrag[s] = f;
    }

    f32x4 acc[4];
#pragma unroll
    for (int nt = 0; nt < 4; ++nt) acc[nt] = (f32x4){0.f, 0.f, 0.f, 0.f};
#pragma unroll
    for (int nt = 0; nt < 4; ++nt) {
      acc[nt] = __builtin_amdgcn_mfma_f32_16x16x32_bf16(afrag[0], bfrag[nt][0],
                                                        acc[nt], 0, 0, 0);
      acc[nt] = __builtin_amdgcn_mfma_f32_16x16x32_bf16(afrag[1], bfrag[nt][1],
                                                        acc[nt], 0, 0, 0);
    }

    // ---- scatter-add: C/D row = quad*4 + reg (pair), col = nt*16 + (lane&15)
    int orow[4];
#pragma unroll
    for (int r = 0; r < 4; ++r) orow[r] = om[pbase + quad * 4 + r];
#pragma unroll
    for (int r = 0; r < 4; ++r) {
      float* op = out + orow[r] * CCH + col;
#pragma unroll
      for (int nt = 0; nt < 4; ++nt)
        atomicAdd(op + nt * 16, acc[nt][r]);
    }
  }
}

extern "C" void kernel_launch(void* const* d_in, const int* in_sizes, int n_in,
                              void* d_out, int out_size, void* d_ws,
                              size_t ws_size, hipStream_t stream) {
  const float* input   = (const float*)d_in[0];
  const float* weight  = (const float*)d_in[1];
  const float* bias    = (const float*)d_in[2];
  const int*   in_map  = (const int*)d_in[3];
  const int*   out_map = (const int*)d_in[4];
  float* out = (float*)d_out;

  // bias broadcast init: 100000*16 float4s / 256 = 6250 blocks
  init_out_kernel<<<(N_POINTS * 16) / 256, 256, 0, stream>>>(bias, out);

  dim3 grid(BX, K_VOL);
  spconv_kernel<<<grid, 256, 0, stream>>>(input, weight, in_map, out_map, out);
}